// Round 24
// baseline (112.493 us; speedup 1.0000x reference)
//
#include <hip/hip_runtime.h>
#include <hip/hip_bf16.h>

// ImageLRU as one GEMM: y[r,:] = W @ x[r,:], W (1024x1024, block-lower-tri)
// built on device. R24: fused-cast GEMM with A stored BF16 in LDS.
//   Diagnosis R18-R23: all fused variants pinned ~96us; LDS pipe ~57% busy
//   moving fp32 A (stage 32K + read 64K per step). Fix: cvt at STAGING via
//   reg path (T14): issue fp32 loads 2 steps ahead -> cvt_pk -> ds_write bf16
//   (quarter-wave-linear, conflict-free). LDS traffic/step 96->48 KB; cvt
//   halved; LDS 32 KB + ~150 VGPR -> 3 blocks/CU.
//   Exact vmcnt FIFO ledger (all loop VMEM in fixed order, sched_barrier
//   pinned): per step [A(t+1)4, W(t+1)2, A(t+2)4] -> vmcnt(4) at boundary;
//   A(t+2) flies across the barrier; raw s_barrier + lgkmcnt(0) only.
//   BM=128 x BN=128, 4 waves 2Mx2N, acc[4][4]; W kg-major [128n][32k] tiles
//   via gld_lds (R7-proven conflict-free); nb-major LPT.
//   1-term precision: y = bf16(X)*bf16(W)  (absmax 8192, thr 32768).

namespace {

typedef __attribute__((ext_vector_type(8))) short short8v;
typedef __attribute__((ext_vector_type(4))) float f32x4;

__device__ inline unsigned short f2bf_rne(float f) {
    unsigned u = __builtin_bit_cast(unsigned, f);
    u += 0x7fffu + ((u >> 16) & 1u);
    return (unsigned short)(u >> 16);
}

__device__ inline void gld_lds16(const unsigned short* g, unsigned short* l) {
    __builtin_amdgcn_global_load_lds(
        (const __attribute__((address_space(1))) unsigned int*)g,
        (__attribute__((address_space(3))) unsigned int*)l, 16, 0, 0);
}

__device__ inline unsigned pk2(float a, float b) {
    __hip_bfloat162 h = __float22bfloat162_rn(make_float2(a, b));
    unsigned r;
    __builtin_memcpy(&r, &h, 4);
    return r;
}

// Tile layouts (kg-major, (row,k) at (k>>3)<<10 | row<<3 | k&7 ushorts):
//   A: [128 rows][32 k] bf16, 4096 ushorts.  W: [128 n][32 k], 4096 ushorts.
// Frag reads (R7-proven conflict-free): off = (lg<<10) + (row<<3).

// ---------------- prep: build Wh (bf16) in [128n][32k] tiles ----------------
__global__ __launch_bounds__(256) void build_w_kernel(
    const float* __restrict__ Lre, const float* __restrict__ Lim,
    const float* __restrict__ Bre, const float* __restrict__ Bim,
    const float* __restrict__ Cre, const float* __restrict__ Cim,
    const float* __restrict__ Dm,
    unsigned short* __restrict__ Wh)
{
    const int i = blockIdx.x >> 6, j = blockIdx.x & 63;
    const int t = threadIdx.x, k = t >> 4, l = t & 15;

    const int n_g = i * 16 + k;        // W row (n dim)
    const int k_g = j * 16 + l;        // W col (k dim)
    const size_t widx = (((size_t)((n_g >> 7) * 32 + (k_g >> 5))) << 12)
                      + (((k_g >> 3) & 3) << 10) + ((n_g & 127) << 3) + (k_g & 7);

    if (j > i) { Wh[widx] = 0; return; }

    __shared__ float2 Bs[16][16];
    __shared__ float2 M[16][16];
    Bs[k][l] = make_float2(Bre[t], Bim[t]);
    M[k][l]  = make_float2(k == l ? 1.f : 0.f, 0.f);
    const int delta = i - j;
    __syncthreads();

    #pragma unroll
    for (int d = 0; d < 6; ++d) {
        const int s = 1 << d;
        if (delta & s) {
            const float lr = Lre[k], li = Lim[k];
            const float2 m0 = M[k][l];
            M[k][l] = make_float2(lr * m0.x - li * m0.y, lr * m0.y + li * m0.x);
            __syncthreads();
        } else if (j + (delta & (s - 1)) >= s) {
            float2 acc = make_float2(0.f, 0.f);
            #pragma unroll
            for (int m = 0; m < 16; ++m) {
                const float2 b = Bs[k][m], v = M[m][l];
                acc.x += b.x * v.x - b.y * v.y;
                acc.y += b.x * v.y + b.y * v.x;
            }
            __syncthreads();
            M[k][l] = acc;
            __syncthreads();
        }
    }

    float w = 0.f;
    #pragma unroll
    for (int m = 0; m < 16; ++m) {
        const float2 v = M[m][l];
        w += Cre[k * 16 + m] * v.x - Cim[k * 16 + m] * v.y;
    }
    if (i == j) w += Dm[t];
    Wh[widx] = f2bf_rne(w);
}

// --- main GEMM: fused cvt-at-staging, A bf16 LDS dbuf, counted vmcnt(4) -----
__global__ __launch_bounds__(256) void gemm_fused_kernel(
    const float* __restrict__ X,
    const unsigned short* __restrict__ Wh,
    float* __restrict__ Y, int mtiles)
{
    __shared__ alignas(16) unsigned short sA[2][4096];   // 16 KB bf16 A
    __shared__ alignas(16) unsigned short sB[2][4096];   // 16 KB bf16 W

    const int bid = blockIdx.x;
    const int nb = 7 - bid / mtiles;   // heavy N-tiles first (LPT), nb-major
    const int mt = bid % mtiles;
    const int t = threadIdx.x;
    const int wid = t >> 6, lane = t & 63;
    const int wr = wid >> 1, wc = wid & 1;     // 2Mx2N wave grid
    const int l15 = lane & 15, lg = lane >> 4;
    const int nt = (nb + 1) * 4;       // K-tiles of 32 (4..32, even)

    f32x4 acc[4][4] = {};

    // frag offsets (ushorts)
    int afo[4], bfo[4];
    #pragma unroll
    for (int mm = 0; mm < 4; ++mm)
        afo[mm] = (lg << 10) + ((wr * 64 + mm * 16 + l15) << 3);
    #pragma unroll
    for (int nn = 0; nn < 4; ++nn)
        bfo[nn] = (lg << 10) + ((wc * 64 + nn * 16 + l15) << 3);

    // A staging: thread owns slots s=t (row0,kq) and s=256+t (row0+64,kq)
    const int row0 = t >> 2, kq = t & 3;
    const float* xr0 = X + (size_t)(mt * 128 + row0) * 1024 + kq * 8;
    const float* xr1 = xr0 + (size_t)64 * 1024;
    const int aw0 = (kq << 10) + (row0 << 3);        // ds_write offsets
    const int aw1 = (kq << 10) + ((row0 + 64) << 3);

    float4 ar0[4], ar1[4];             // named reg sets: even / odd tiles

    auto issueA = [&](float4* ar, int tk) {          // 4 global float4 loads
        const float* s0 = xr0 + tk * 32;
        const float* s1 = xr1 + tk * 32;
        ar[0] = *reinterpret_cast<const float4*>(s0);
        ar[1] = *reinterpret_cast<const float4*>(s0 + 4);
        ar[2] = *reinterpret_cast<const float4*>(s1);
        ar[3] = *reinterpret_cast<const float4*>(s1 + 4);
    };
    auto writeA = [&](unsigned short* bufA, const float4* ar) {  // cvt + 2 b128
        short8v v0, v1;
        unsigned u0[4] = { pk2(ar[0].x, ar[0].y), pk2(ar[0].z, ar[0].w),
                           pk2(ar[1].x, ar[1].y), pk2(ar[1].z, ar[1].w) };
        unsigned u1[4] = { pk2(ar[2].x, ar[2].y), pk2(ar[2].z, ar[2].w),
                           pk2(ar[3].x, ar[3].y), pk2(ar[3].z, ar[3].w) };
        __builtin_memcpy(&v0, u0, 16);
        __builtin_memcpy(&v1, u1, 16);
        *reinterpret_cast<short8v*>(bufA + aw0) = v0;
        *reinterpret_cast<short8v*>(bufA + aw1) = v1;
    };
    auto stageW = [&](unsigned short* bufB, int tk) {            // 2 gld_lds
        const unsigned short* wb = Wh + (((size_t)(nb * 32 + tk)) << 12);
        gld_lds16(wb + t * 8,        bufB + t * 8);
        gld_lds16(wb + 2048 + t * 8, bufB + 2048 + t * 8);
    };
    auto compute = [&](const unsigned short* bufA, const unsigned short* bufB) {
        short8v ah[4], bh[4];
        #pragma unroll
        for (int mm = 0; mm < 4; ++mm)
            ah[mm] = *reinterpret_cast<const short8v*>(bufA + afo[mm]);
        #pragma unroll
        for (int nn = 0; nn < 4; ++nn)
            bh[nn] = *reinterpret_cast<const short8v*>(bufB + bfo[nn]);
        __builtin_amdgcn_s_setprio(1);
        #pragma unroll
        for (int mm = 0; mm < 4; ++mm)
            #pragma unroll
            for (int nn = 0; nn < 4; ++nn)
                acc[mm][nn] = __builtin_amdgcn_mfma_f32_16x16x32_bf16(
                    ah[mm], bh[nn], acc[mm][nn], 0, 0, 0);
        __builtin_amdgcn_s_setprio(0);
    };

    // ---- prologue: FIFO = [A(0)x4, W(0)x2, A(1)x4] ----
    issueA(ar0, 0);
    stageW(sB[0], 0);
    issueA(ar1, 1);
    asm volatile("s_waitcnt vmcnt(4)" ::: "memory");  // A0+W0 landed; A1 flies
    __builtin_amdgcn_sched_barrier(0);
    writeA(sA[0], ar0);                               // tile 0 -> sA0
    asm volatile("s_waitcnt lgkmcnt(0)" ::: "memory");
    __builtin_amdgcn_s_barrier();
    __builtin_amdgcn_sched_barrier(0);

    for (int tk = 0; tk < nt; tk += 2) {
        // ===== even step tk: compute (sA0, sB0) =====
        stageW(sB[1], tk + 1);                        // W(t+1): 2 gld
        __builtin_amdgcn_sched_barrier(0);
        if (tk + 2 < nt) issueA(ar0, tk + 2);         // A(t+2): 4 ld (set0)
        __builtin_amdgcn_sched_barrier(0);
        compute(sA[0], sB[0]);
        if (tk + 2 < nt) {
            asm volatile("s_waitcnt vmcnt(4)" ::: "memory");  // A(t+2) flies
        } else {
            asm volatile("s_waitcnt vmcnt(0)" ::: "memory");
        }
        __builtin_amdgcn_sched_barrier(0);
        writeA(sA[1], ar1);                           // tile t+1 -> sA1
        asm volatile("s_waitcnt lgkmcnt(0)" ::: "memory");
        __builtin_amdgcn_s_barrier();
        __builtin_amdgcn_sched_barrier(0);

        // ===== odd step tk+1: compute (sA1, sB1) =====
        if (tk + 2 < nt) {
            stageW(sB[0], tk + 2);                    // W(t+2): 2 gld
            __builtin_amdgcn_sched_barrier(0);
            if (tk + 3 < nt) issueA(ar1, tk + 3);     // A(t+3): 4 ld (set1)
            __builtin_amdgcn_sched_barrier(0);
        }
        compute(sA[1], sB[1]);
        if (tk + 2 < nt) {
            if (tk + 3 < nt) {
                asm volatile("s_waitcnt vmcnt(4)" ::: "memory");
            } else {
                asm volatile("s_waitcnt vmcnt(0)" ::: "memory");
            }
            __builtin_amdgcn_sched_barrier(0);
            writeA(sA[0], ar0);                       // tile t+2 -> sA0
            asm volatile("s_waitcnt lgkmcnt(0)" ::: "memory");
            __builtin_amdgcn_s_barrier();
            __builtin_amdgcn_sched_barrier(0);
        }
    }

    // ---- epilogue: C/D layout col=lane&15, row=(lane>>4)*4+q ----
    #pragma unroll
    for (int mm = 0; mm < 4; ++mm) {
        const int grow = mt * 128 + wr * 64 + mm * 16 + lg * 4;
        #pragma unroll
        for (int nn = 0; nn < 4; ++nn) {
            const int gcol = nb * 128 + wc * 64 + nn * 16 + l15;
            #pragma unroll
            for (int q = 0; q < 4; ++q)
                Y[(size_t)(grow + q) * 1024 + gcol] = acc[mm][nn][q];
        }
    }
}

} // namespace

extern "C" void kernel_launch(void* const* d_in, const int* in_sizes, int n_in,
                              void* d_out, int out_size, void* d_ws, size_t ws_size,
                              hipStream_t stream) {
    const float* x   = (const float*)d_in[0];
    const float* Lre = (const float*)d_in[1];
    const float* Lim = (const float*)d_in[2];
    const float* Bre = (const float*)d_in[3];
    const float* Bim = (const float*)d_in[4];
    const float* Cre = (const float*)d_in[5];
    const float* Cim = (const float*)d_in[6];
    const float* Dm  = (const float*)d_in[7];
    float* y = (float*)d_out;

    const int positions = in_sizes[0] / 1024;          // 32768
    const int mtiles = positions / 128;                // 256

    unsigned short* Wh = (unsigned short*)d_ws;        // 2 MB

    build_w_kernel<<<4096, 256, 0, stream>>>(Lre, Lim, Bre, Bim, Cre, Cim, Dm, Wh);
    gemm_fused_kernel<<<mtiles * 8, 256, 0, stream>>>(x, Wh, y, mtiles);
}